// Round 11
// baseline (119.912 us; speedup 1.0000x reference)
//
#include <hip/hip_runtime.h>
#include <stdint.h>

#define NPTS   4096
#define NSKIP  16384
#define CCH    256
#define CSK    128
#define DIN    384
#define HDIM   256
#define BIGF   1e10f

typedef unsigned short u16;
typedef __attribute__((ext_vector_type(8))) short short8;
typedef __attribute__((ext_vector_type(4))) float floatx4;

__device__ __forceinline__ u16 f2bf(float f) {
    union { float f; uint32_t u; } c; c.f = f;
    uint32_t u = c.u;
    return (u16)((u + 0x7FFFu + ((u >> 16) & 1u)) >> 16);
}

__device__ __forceinline__ double pkkey(float d, int j) {
    return __hiloint2double(__float_as_int(d), j);
}

// ---------------------------------------------------------------------------
// k1: prep+knn (identical to R2 best): blocks 0-47 pack W1 (ntile-major),
// 48-79 pack W2; blocks 80.. KNN (8 pts/block, 32 threads/pt).
// ---------------------------------------------------------------------------
__global__ __launch_bounds__(256) void prep_knn_kernel(
    const float* __restrict__ W1, const float* __restrict__ W2,
    u16* __restrict__ W1p, u16* __restrict__ W2p,
    const float* __restrict__ pos, const int* __restrict__ batch,
    const float* __restrict__ pos_skip, const int* __restrict__ batch_skip,
    int* __restrict__ idx3, float* __restrict__ w3)
{
    const int bid = blockIdx.x;
    const int t = threadIdx.x;

    if (bid < 80) {
        const float* W = (bid < 48) ? W1 : W2;
        u16* Wp       = (bid < 48) ? W1p : W2p;
        const int KT  = (bid < 48) ? 12 : 8;
        const int g   = ((bid < 48) ? bid : (bid - 48)) * 256 + t;

        const int lane = g & 63;
        const int kt = (g >> 6) % KT;
        const int nt = (g >> 6) / KT;
        const int kbase = kt * 32 + (lane >> 4) * 8;
        const int n = nt * 16 + (lane & 15);
        u16 v[8];
#pragma unroll
        for (int j = 0; j < 8; ++j) v[j] = f2bf(W[(size_t)(kbase + j) * HDIM + n]);
#pragma unroll
        for (int j = 0; j < 8; ++j) Wp[(size_t)g * 8 + j] = v[j];
        return;
    }

    __shared__ int sRange[5];
    if (t < 5) {
        int lo = 0, hi = NPTS;
        while (lo < hi) {
            const int m = (lo + hi) >> 1;
            if (batch[m] < t) lo = m + 1; else hi = m;
        }
        sRange[t] = lo;
    }
    __syncthreads();

    const int i = (bid - 80) * 8 + (t >> 5);
    const int sub = t & 31;
    const int b = batch_skip[i];
    const int start = sRange[b], end = sRange[b + 1];

    const float px = pos_skip[i * 3 + 0];
    const float py = pos_skip[i * 3 + 1];
    const float pz = pos_skip[i * 3 + 2];

    const double BIGKEY = pkkey(BIGF, 0x7FFFFFFF);
    double k0 = BIGKEY, k1 = BIGKEY, k2 = BIGKEY;

    for (int j = start + sub; j < end; j += 32) {
        const float qx = pos[j * 3 + 0];
        const float qy = pos[j * 3 + 1];
        const float qz = pos[j * 3 + 2];
        const float dx = __fsub_rn(px, qx);
        const float dy = __fsub_rn(py, qy);
        const float dz = __fsub_rn(pz, qz);
        const float dd = __fadd_rn(__fadd_rn(__fmul_rn(dx, dx), __fmul_rn(dy, dy)),
                                   __fmul_rn(dz, dz));
        const double kk = pkkey(dd, j);
        const double u0 = fmax(k0, kk); k0 = fmin(k0, kk);
        const double u1 = fmax(k1, u0); k1 = fmin(k1, u0);
        k2 = fmin(k2, u1);
    }

#pragma unroll
    for (int m = 1; m < 32; m <<= 1) {
        const double o0 = __shfl_xor(k0, m);
        const double o1 = __shfl_xor(k1, m);
        const double o2 = __shfl_xor(k2, m);
        double u0 = fmax(k0, o0); k0 = fmin(k0, o0);
        double u1 = fmax(k1, u0); k1 = fmin(k1, u0);
        k2 = fmin(k2, u1);
        u1 = fmax(k1, o1); k1 = fmin(k1, o1);
        k2 = fmin(k2, u1);
        k2 = fmin(k2, o2);
    }

    if (sub == 0) {
        const float d0 = __int_as_float(__double2hiint(k0));
        const float d1 = __int_as_float(__double2hiint(k1));
        const float d2 = __int_as_float(__double2hiint(k2));
        const float w0 = 1.0f / fmaxf(d0, 1e-16f);
        const float w1 = 1.0f / fmaxf(d1, 1e-16f);
        const float w2 = 1.0f / fmaxf(d2, 1e-16f);
        const float inv = 1.0f / (w0 + w1 + w2);
        idx3[i * 3 + 0] = __double2loint(k0);
        idx3[i * 3 + 1] = __double2loint(k1);
        idx3[i * 3 + 2] = __double2loint(k2);
        w3[i * 3 + 0] = w0 * inv; w3[i * 3 + 1] = w1 * inv; w3[i * 3 + 2] = w2 * inv;
    }
}

// ---------------------------------------------------------------------------
// k2 (R17): precompute Z = x @ W1[0:256,:] (blocks 0..127) and
// S = x_skip @ W1[256:384,:] (blocks 128..639), both f32 in ws.
// Uses W1p's kt-slices: Z -> kt 0..7, S -> kt 8..11. No bias/relu here.
// ---------------------------------------------------------------------------
__global__ __launch_bounds__(512) void zs_kernel(
    const float* __restrict__ x, const float* __restrict__ x_skip,
    const u16* __restrict__ W1p,
    float* __restrict__ Zb, float* __restrict__ Sb)
{
    __shared__ u16 sA[32 * 264];
    __shared__ float sOut[32 * 256];
    const int t = threadIdx.x;
    const int wave = t >> 6, lane = t & 63;
    const int quad = lane >> 4, ml = lane & 15;
    const bool isZ = blockIdx.x < 128;
    const int brow = (isZ ? blockIdx.x : blockIdx.x - 128) * 32;

    if (isZ) {
        // pack x tile [32 x 256] -> bf16, stride 264
#pragma unroll
        for (int k = 0; k < 4; ++k) {
            const int g = t + 512 * k;
            const int row = g >> 6, c4 = g & 63;
            const float4 v = *(const float4*)(x + (size_t)(brow + row) * CCH + c4 * 4);
            uint2 pk;
            pk.x = (uint32_t)f2bf(v.x) | ((uint32_t)f2bf(v.y) << 16);
            pk.y = (uint32_t)f2bf(v.z) | ((uint32_t)f2bf(v.w) << 16);
            *(uint2*)(sA + row * 264 + c4 * 4) = pk;
        }
    } else {
        // pack x_skip tile [32 x 128] -> bf16, stride 136
#pragma unroll
        for (int k = 0; k < 2; ++k) {
            const int g = t + 512 * k;
            const int row = g >> 5, c4 = g & 31;
            const float4 v = *(const float4*)(x_skip + (size_t)(brow + row) * CSK + c4 * 4);
            uint2 pk;
            pk.x = (uint32_t)f2bf(v.x) | ((uint32_t)f2bf(v.y) << 16);
            pk.y = (uint32_t)f2bf(v.z) | ((uint32_t)f2bf(v.w) << 16);
            *(uint2*)(sA + row * 136 + c4 * 4) = pk;
        }
    }
    __syncthreads();

    floatx4 acc[2][2] = {};
    if (isZ) {
        const u16* aA = sA + ml * 264 + quad * 8;
        for (int kt = 0; kt < 8; ++kt) {
            short8 a0 = *(const short8*)(aA + kt * 32);
            short8 a1 = *(const short8*)(aA + 16 * 264 + kt * 32);
#pragma unroll
            for (int nt = 0; nt < 2; ++nt) {
                const int ntile = wave * 2 + nt;
                short8 bfr = *(const short8*)(W1p + (size_t)((ntile * 12 + kt) * 64 + lane) * 8);
                acc[0][nt] = __builtin_amdgcn_mfma_f32_16x16x32_bf16(a0, bfr, acc[0][nt], 0, 0, 0);
                acc[1][nt] = __builtin_amdgcn_mfma_f32_16x16x32_bf16(a1, bfr, acc[1][nt], 0, 0, 0);
            }
        }
    } else {
        const u16* aA = sA + ml * 136 + quad * 8;
        for (int kt = 0; kt < 4; ++kt) {
            short8 a0 = *(const short8*)(aA + kt * 32);
            short8 a1 = *(const short8*)(aA + 16 * 136 + kt * 32);
#pragma unroll
            for (int nt = 0; nt < 2; ++nt) {
                const int ntile = wave * 2 + nt;
                short8 bfr = *(const short8*)(W1p + (size_t)((ntile * 12 + 8 + kt) * 64 + lane) * 8);
                acc[0][nt] = __builtin_amdgcn_mfma_f32_16x16x32_bf16(a0, bfr, acc[0][nt], 0, 0, 0);
                acc[1][nt] = __builtin_amdgcn_mfma_f32_16x16x32_bf16(a1, bfr, acc[1][nt], 0, 0, 0);
            }
        }
    }

#pragma unroll
    for (int mt = 0; mt < 2; ++mt) {
#pragma unroll
        for (int nt = 0; nt < 2; ++nt) {
            const int n = (wave * 2 + nt) * 16 + ml;
#pragma unroll
            for (int r = 0; r < 4; ++r) {
                const int m = mt * 16 + quad * 4 + r;
                sOut[m * 256 + n] = acc[mt][nt][r];
            }
        }
    }
    __syncthreads();
    {
        float* dst = (isZ ? Zb : Sb) + (size_t)brow * 256;
#pragma unroll
        for (int k = 0; k < 4; ++k) {
            const int e = t + 512 * k;
            *(float4*)(dst + e * 4) = *(const float4*)(sOut + e * 4);
        }
    }
}

// ---------------------------------------------------------------------------
// k3 (R17): fused-lite, 32 rows/block, 512 blocks, 1024 threads.
// h = relu( sum_i w_i * Z[idx_i] + S[row] + b1 ) -> bf16 -> GEMM2 only.
// GEMM1 deleted from the serial chain via linearity of interpolation.
// ---------------------------------------------------------------------------
__global__ __launch_bounds__(1024, 8) void fused_mlp_kernel(
    const float* __restrict__ Zb, const float* __restrict__ Sb,
    const int* __restrict__ idx3, const float* __restrict__ w3,
    const u16* __restrict__ W2p, const float* __restrict__ b1,
    const float* __restrict__ b2,
    const float* __restrict__ pos_skip, const int* __restrict__ batch_skip,
    float* __restrict__ out)
{
    __shared__ u16 sA[32 * 264];     // h tile bf16
    __shared__ float sOut[32 * 256]; // f32 epilogue staging
    const int t = threadIdx.x;
    const int row0 = blockIdx.x * 32;
    const int wave = t >> 6, lane = t & 63;
    const int quad = lane >> 4, ml = lane & 15;
    const int rl = t >> 5, c8 = t & 31;   // 32 threads/row, 8 cols each

    // --- S preload (independent stream, issues first) ---
    const float* Sp = Sb + (size_t)(row0 + rl) * 256 + c8 * 8;
    const float4 s0 = *(const float4*)Sp;
    const float4 s1 = *(const float4*)(Sp + 4);

    // --- Z gather + combine ---
    const int R = row0 + rl;
    const int i0 = idx3[R * 3 + 0], i1 = idx3[R * 3 + 1], i2 = idx3[R * 3 + 2];
    const float w0 = w3[R * 3 + 0], w1 = w3[R * 3 + 1], w2 = w3[R * 3 + 2];
    const float4 z00 = *(const float4*)(Zb + (size_t)i0 * 256 + c8 * 8);
    const float4 z01 = *(const float4*)(Zb + (size_t)i0 * 256 + c8 * 8 + 4);
    const float4 z10 = *(const float4*)(Zb + (size_t)i1 * 256 + c8 * 8);
    const float4 z11 = *(const float4*)(Zb + (size_t)i1 * 256 + c8 * 8 + 4);
    const float4 z20 = *(const float4*)(Zb + (size_t)i2 * 256 + c8 * 8);
    const float4 z21 = *(const float4*)(Zb + (size_t)i2 * 256 + c8 * 8 + 4);
    const float4 bb0 = *(const float4*)(b1 + c8 * 8);
    const float4 bb1 = *(const float4*)(b1 + c8 * 8 + 4);

    float h[8];
    h[0] = w0 * z00.x + w1 * z10.x + w2 * z20.x + s0.x + bb0.x;
    h[1] = w0 * z00.y + w1 * z10.y + w2 * z20.y + s0.y + bb0.y;
    h[2] = w0 * z00.z + w1 * z10.z + w2 * z20.z + s0.z + bb0.z;
    h[3] = w0 * z00.w + w1 * z10.w + w2 * z20.w + s0.w + bb0.w;
    h[4] = w0 * z01.x + w1 * z11.x + w2 * z21.x + s1.x + bb1.x;
    h[5] = w0 * z01.y + w1 * z11.y + w2 * z21.y + s1.y + bb1.y;
    h[6] = w0 * z01.z + w1 * z11.z + w2 * z21.z + s1.z + bb1.z;
    h[7] = w0 * z01.w + w1 * z11.w + w2 * z21.w + s1.w + bb1.w;
    uint4 pk;
    pk.x = (uint32_t)f2bf(fmaxf(h[0], 0.0f)) | ((uint32_t)f2bf(fmaxf(h[1], 0.0f)) << 16);
    pk.y = (uint32_t)f2bf(fmaxf(h[2], 0.0f)) | ((uint32_t)f2bf(fmaxf(h[3], 0.0f)) << 16);
    pk.z = (uint32_t)f2bf(fmaxf(h[4], 0.0f)) | ((uint32_t)f2bf(fmaxf(h[5], 0.0f)) << 16);
    pk.w = (uint32_t)f2bf(fmaxf(h[6], 0.0f)) | ((uint32_t)f2bf(fmaxf(h[7], 0.0f)) << 16);
    *(uint4*)(sA + rl * 264 + c8 * 8) = pk;
    __syncthreads();

    // --- GEMM2: h[32x256] @ W2; 1 ntile per wave, 16 waves ---
    floatx4 acc2[2] = {};
    {
        const u16* aH = sA + ml * 264 + quad * 8;
        for (int kt = 0; kt < 8; ++kt) {
            short8 a0 = *(const short8*)(aH + kt * 32);
            short8 a1 = *(const short8*)(aH + 16 * 264 + kt * 32);
            short8 bfr = *(const short8*)(W2p + (size_t)((wave * 8 + kt) * 64 + lane) * 8);
            acc2[0] = __builtin_amdgcn_mfma_f32_16x16x32_bf16(a0, bfr, acc2[0], 0, 0, 0);
            acc2[1] = __builtin_amdgcn_mfma_f32_16x16x32_bf16(a1, bfr, acc2[1], 0, 0, 0);
        }
    }

    // --- epilogue ---
    {
        const int n = wave * 16 + ml;
        const float bv = b2[n];
#pragma unroll
        for (int mt = 0; mt < 2; ++mt) {
#pragma unroll
            for (int r = 0; r < 4; ++r) {
                const int m = mt * 16 + quad * 4 + r;
                sOut[m * 256 + n] = fmaxf(acc2[mt][r] + bv, 0.0f);
            }
        }
    }
    __syncthreads();
    {
        float* dst = out + (size_t)row0 * HDIM;
#pragma unroll
        for (int k = 0; k < 2; ++k) {
            const int e = t + 1024 * k;
            *(float4*)(dst + e * 4) = *(const float4*)(sOut + e * 4);
        }
    }

    // --- tail: 128 flat elems per block ---
    if (t < 128) {
        const int e = blockIdx.x * 128 + t;
        const size_t base = (size_t)NSKIP * HDIM;
        if (e < NSKIP * 3) out[base + e] = pos_skip[e];
        else               out[base + e] = (float)batch_skip[e - NSKIP * 3];
    }
}

extern "C" void kernel_launch(void* const* d_in, const int* in_sizes, int n_in,
                              void* d_out, int out_size, void* d_ws, size_t ws_size,
                              hipStream_t stream) {
    const float* x         = (const float*)d_in[0];
    const float* pos       = (const float*)d_in[1];
    const int*   batch     = (const int*)d_in[2];
    const float* x_skip    = (const float*)d_in[3];
    const float* pos_skip  = (const float*)d_in[4];
    const int*   batch_skip= (const int*)d_in[5];
    const float* W1        = (const float*)d_in[6];
    const float* b1        = (const float*)d_in[7];
    const float* W2        = (const float*)d_in[8];
    const float* b2        = (const float*)d_in[9];
    float* out = (float*)d_out;

    // ws layout:
    char* ws = (char*)d_ws;
    u16*    W1p   = (u16*)ws;                      // 196608 B
    u16*    W2p   = (u16*)(ws + 196608);           // 131072 B
    int*    idx3  = (int*)(ws + 327680);           // 196608 B
    float*  w3    = (float*)(ws + 524288);         // 196608 B
    float*  Zb    = (float*)(ws + 720896);         // 4194304 B
    float*  Sb    = (float*)(ws + 4915200);        // 16777216 B (~20.7 MB total)

    prep_knn_kernel<<<80 + NSKIP / 8, 256, 0, stream>>>(W1, W2, W1p, W2p,
                                                        pos, batch,
                                                        pos_skip, batch_skip,
                                                        idx3, w3);
    zs_kernel<<<128 + NSKIP / 32, 512, 0, stream>>>(x, x_skip, W1p, Zb, Sb);
    fused_mlp_kernel<<<NSKIP / 32, 1024, 0, stream>>>(Zb, Sb, idx3, w3,
                                                      W2p, b1, b2,
                                                      pos_skip, batch_skip, out);
}

// Round 12
// 108.198 us; speedup vs baseline: 1.1083x; 1.1083x over previous
//
#include <hip/hip_runtime.h>
#include <stdint.h>

#define NPTS   4096
#define NSKIP  16384
#define CCH    256
#define CSK    128
#define DIN    384
#define HDIM   256
#define BIGF   1e10f

typedef unsigned short u16;
typedef __attribute__((ext_vector_type(8))) short short8;
typedef __attribute__((ext_vector_type(4))) float floatx4;

__device__ __forceinline__ u16 f2bf(float f) {
    union { float f; uint32_t u; } c; c.f = f;
    uint32_t u = c.u;
    return (u16)((u + 0x7FFFu + ((u >> 16) & 1u)) >> 16);
}

// Pack (non-negative fp32 dist, idx) into a positive double whose numeric
// order == (dist, idx) lexicographic order (exact top_k tie semantics).
__device__ __forceinline__ double pkkey(float d, int j) {
    return __hiloint2double(__float_as_int(d), j);
}

// ---------------------------------------------------------------------------
// k1 (R18): prep only — 80 blocks. Blocks 0-47 pack W1, 48-79 pack W2
// (ntile-major MFMA B-fragment layout); blocks 48-63 also build pos4.
// ---------------------------------------------------------------------------
__global__ __launch_bounds__(256) void prep_kernel(
    const float* __restrict__ W1, const float* __restrict__ W2,
    u16* __restrict__ W1p, u16* __restrict__ W2p,
    const float* __restrict__ pos, float4* __restrict__ pos4)
{
    const int bid = blockIdx.x;
    const int t = threadIdx.x;

    const float* W = (bid < 48) ? W1 : W2;
    u16* Wp       = (bid < 48) ? W1p : W2p;
    const int KT  = (bid < 48) ? 12 : 8;
    const int g   = ((bid < 48) ? bid : (bid - 48)) * 256 + t;

    const int lane = g & 63;
    const int kt = (g >> 6) % KT;
    const int nt = (g >> 6) / KT;
    const int kbase = kt * 32 + (lane >> 4) * 8;
    const int n = nt * 16 + (lane & 15);
    u16 v[8];
#pragma unroll
    for (int j = 0; j < 8; ++j) v[j] = f2bf(W[(size_t)(kbase + j) * HDIM + n]);
#pragma unroll
    for (int j = 0; j < 8; ++j) Wp[(size_t)g * 8 + j] = v[j];

    if (bid >= 48 && bid < 64) {
        const int p = (bid - 48) * 256 + t;
        pos4[p] = make_float4(pos[p * 3 + 0], pos[p * 3 + 1], pos[p * 3 + 2], 0.0f);
    }
}

// ---------------------------------------------------------------------------
// k2 (R18): mega kernel — 32 rows/block, 512 blocks, 1024 threads (16 waves),
// __launch_bounds__(1024, 8). Phases per block:
//   A: KNN for its 32 rows (32 threads/pt — proven standalone geometry;
//      aggregate 32 waves/CU == standalone knn's occupancy) -> LDS idx/w.
//   B: interp gather + bf16 pack + skip concat -> sA.
//   C: GEMM1 (12 kt) -> h relu pack -> GEMM2 (8 kt) -> coalesced epilogue.
// Different blocks' A (VALU) and C (MFMA) phases co-schedule per CU; fused's
// pipes were measured ~90% idle, so A should be largely absorbed.
// ---------------------------------------------------------------------------
__global__ __launch_bounds__(1024, 8) void mega_kernel(
    const float* __restrict__ x, const float* __restrict__ x_skip,
    const float4* __restrict__ pos4, const int* __restrict__ batch,
    const u16* __restrict__ W1p, const float* __restrict__ b1,
    const u16* __restrict__ W2p, const float* __restrict__ b2,
    const float* __restrict__ pos_skip, const int* __restrict__ batch_skip,
    float* __restrict__ out)
{
    __shared__ u16 sA[32 * 392];     // 25088 B; reused as h[32][264]
    __shared__ float sOut[32 * 256]; // 32768 B f32 epilogue staging
    __shared__ int   sIdx[32 * 3];
    __shared__ float sWgt[32 * 3];
    __shared__ int   sRange[5];
    const int t = threadIdx.x;
    const int row0 = blockIdx.x * 32;
    const int wave = t >> 6, lane = t & 63;
    const int quad = lane >> 4, ml = lane & 15;

    // --- batch range table (binary search; L1-resident batch array) ---
    if (t < 5) {
        int lo = 0, hi = NPTS;
        while (lo < hi) {
            const int m = (lo + hi) >> 1;
            if (batch[m] < t) lo = m + 1; else hi = m;
        }
        sRange[t] = lo;
    }
    // --- skip copy first (independent): loads issue under the knn scan ---
    {
        const int row = t >> 5, c4 = t & 31;
        const float4 v = *(const float4*)(x_skip + (size_t)(row0 + row) * CSK + c4 * 4);
        uint2 pk;
        pk.x = (uint32_t)f2bf(v.x) | ((uint32_t)f2bf(v.y) << 16);
        pk.y = (uint32_t)f2bf(v.z) | ((uint32_t)f2bf(v.w) << 16);
        *(uint2*)(sA + row * 392 + CCH + c4 * 4) = pk;
    }
    __syncthreads();

    // --- Phase A: KNN (32 threads/pt, stride-32 scan, f64-key top-3) ---
    {
        const int rl = t >> 5;          // 0..31
        const int sub = t & 31;
        const int i = row0 + rl;
        const int b = batch_skip[i];
        const int start = sRange[b], end = sRange[b + 1];

        const float px = pos_skip[i * 3 + 0];
        const float py = pos_skip[i * 3 + 1];
        const float pz = pos_skip[i * 3 + 2];

        const double BIGKEY = pkkey(BIGF, 0x7FFFFFFF);
        double k0 = BIGKEY, k1 = BIGKEY, k2 = BIGKEY;

        for (int j = start + sub; j < end; j += 32) {
            const float4 q = pos4[j];
            const float dx = __fsub_rn(px, q.x);
            const float dy = __fsub_rn(py, q.y);
            const float dz = __fsub_rn(pz, q.z);
            const float dd = __fadd_rn(__fadd_rn(__fmul_rn(dx, dx), __fmul_rn(dy, dy)),
                                       __fmul_rn(dz, dz));
            const double kk = pkkey(dd, j);
            const double u0 = fmax(k0, kk); k0 = fmin(k0, kk);
            const double u1 = fmax(k1, u0); k1 = fmin(k1, u0);
            k2 = fmin(k2, u1);
        }

#pragma unroll
        for (int m = 1; m < 32; m <<= 1) {
            const double o0 = __shfl_xor(k0, m);
            const double o1 = __shfl_xor(k1, m);
            const double o2 = __shfl_xor(k2, m);
            double u0 = fmax(k0, o0); k0 = fmin(k0, o0);
            double u1 = fmax(k1, u0); k1 = fmin(k1, u0);
            k2 = fmin(k2, u1);
            u1 = fmax(k1, o1); k1 = fmin(k1, o1);
            k2 = fmin(k2, u1);
            k2 = fmin(k2, o2);
        }

        if (sub == 0) {
            const float d0 = __int_as_float(__double2hiint(k0));
            const float d1 = __int_as_float(__double2hiint(k1));
            const float d2 = __int_as_float(__double2hiint(k2));
            const float w0 = 1.0f / fmaxf(d0, 1e-16f);
            const float w1 = 1.0f / fmaxf(d1, 1e-16f);
            const float w2 = 1.0f / fmaxf(d2, 1e-16f);
            const float inv = 1.0f / (w0 + w1 + w2);
            sIdx[rl * 3 + 0] = __double2loint(k0);
            sIdx[rl * 3 + 1] = __double2loint(k1);
            sIdx[rl * 3 + 2] = __double2loint(k2);
            sWgt[rl * 3 + 0] = w0 * inv;
            sWgt[rl * 3 + 1] = w1 * inv;
            sWgt[rl * 3 + 2] = w2 * inv;
        }
    }
    __syncthreads();

    // --- Phase B: interp gather, 2 slots/thread ---
#pragma unroll
    for (int k = 0; k < 2; ++k) {
        const int g = t + 1024 * k;
        const int row = g >> 6, c4 = g & 63;
        const int i0 = sIdx[row * 3 + 0], i1 = sIdx[row * 3 + 1], i2 = sIdx[row * 3 + 2];
        const float w0 = sWgt[row * 3 + 0], w1 = sWgt[row * 3 + 1], w2 = sWgt[row * 3 + 2];
        const float4 v0 = *(const float4*)(x + (size_t)i0 * CCH + c4 * 4);
        const float4 v1 = *(const float4*)(x + (size_t)i1 * CCH + c4 * 4);
        const float4 v2 = *(const float4*)(x + (size_t)i2 * CCH + c4 * 4);
        const float a  = w0 * v0.x + w1 * v1.x + w2 * v2.x;
        const float bq = w0 * v0.y + w1 * v1.y + w2 * v2.y;
        const float cq = w0 * v0.z + w1 * v1.z + w2 * v2.z;
        const float dq = w0 * v0.w + w1 * v1.w + w2 * v2.w;
        uint2 pk;
        pk.x = (uint32_t)f2bf(a)  | ((uint32_t)f2bf(bq) << 16);
        pk.y = (uint32_t)f2bf(cq) | ((uint32_t)f2bf(dq) << 16);
        *(uint2*)(sA + row * 392 + c4 * 4) = pk;
    }
    __syncthreads();

    // --- Phase C1: GEMM1 A[32x384] @ W1 -> h[32x256]; 1 ntile/wave ---
    floatx4 acc[2] = {};
    {
        const u16* aA = sA + ml * 392 + quad * 8;
        for (int kt = 0; kt < 12; ++kt) {
            short8 a0 = *(const short8*)(aA + kt * 32);
            short8 a1 = *(const short8*)(aA + 16 * 392 + kt * 32);
            short8 bfr = *(const short8*)(W1p + (size_t)((wave * 12 + kt) * 64 + lane) * 8);
            acc[0] = __builtin_amdgcn_mfma_f32_16x16x32_bf16(a0, bfr, acc[0], 0, 0, 0);
            acc[1] = __builtin_amdgcn_mfma_f32_16x16x32_bf16(a1, bfr, acc[1], 0, 0, 0);
        }
    }
    __syncthreads();

    // --- h = relu(acc + b1) -> LDS bf16 [32 x 264] ---
    {
        const int n = wave * 16 + ml;
        const float bv = b1[n];
#pragma unroll
        for (int mt = 0; mt < 2; ++mt) {
#pragma unroll
            for (int r = 0; r < 4; ++r) {
                const int m = mt * 16 + quad * 4 + r;
                sA[m * 264 + n] = f2bf(fmaxf(acc[mt][r] + bv, 0.0f));
            }
        }
    }
    __syncthreads();

    // --- Phase C2: GEMM2 h[32x256] @ W2; 1 ntile/wave ---
    floatx4 acc2[2] = {};
    {
        const u16* aH = sA + ml * 264 + quad * 8;
        for (int kt = 0; kt < 8; ++kt) {
            short8 a0 = *(const short8*)(aH + kt * 32);
            short8 a1 = *(const short8*)(aH + 16 * 264 + kt * 32);
            short8 bfr = *(const short8*)(W2p + (size_t)((wave * 8 + kt) * 64 + lane) * 8);
            acc2[0] = __builtin_amdgcn_mfma_f32_16x16x32_bf16(a0, bfr, acc2[0], 0, 0, 0);
            acc2[1] = __builtin_amdgcn_mfma_f32_16x16x32_bf16(a1, bfr, acc2[1], 0, 0, 0);
        }
    }

    // --- epilogue: fragments -> sOut (f32) -> coalesced contiguous stores ---
    {
        const int n = wave * 16 + ml;
        const float bv = b2[n];
#pragma unroll
        for (int mt = 0; mt < 2; ++mt) {
#pragma unroll
            for (int r = 0; r < 4; ++r) {
                const int m = mt * 16 + quad * 4 + r;
                sOut[m * 256 + n] = fmaxf(acc2[mt][r] + bv, 0.0f);
            }
        }
    }
    __syncthreads();
    {
        float* dst = out + (size_t)row0 * HDIM;
#pragma unroll
        for (int k = 0; k < 2; ++k) {
            const int e = t + 1024 * k;
            *(float4*)(dst + e * 4) = *(const float4*)(sOut + e * 4);
        }
    }

    // --- tail: 128 flat elems per block ---
    if (t < 128) {
        const int e = blockIdx.x * 128 + t;
        const size_t base = (size_t)NSKIP * HDIM;
        if (e < NSKIP * 3) out[base + e] = pos_skip[e];
        else               out[base + e] = (float)batch_skip[e - NSKIP * 3];
    }
}

extern "C" void kernel_launch(void* const* d_in, const int* in_sizes, int n_in,
                              void* d_out, int out_size, void* d_ws, size_t ws_size,
                              hipStream_t stream) {
    const float* x         = (const float*)d_in[0];
    const float* pos       = (const float*)d_in[1];
    const int*   batch     = (const int*)d_in[2];
    const float* x_skip    = (const float*)d_in[3];
    const float* pos_skip  = (const float*)d_in[4];
    const int*   batch_skip= (const int*)d_in[5];
    const float* W1        = (const float*)d_in[6];
    const float* b1        = (const float*)d_in[7];
    const float* W2        = (const float*)d_in[8];
    const float* b2        = (const float*)d_in[9];
    float* out = (float*)d_out;

    // ws layout:
    char* ws = (char*)d_ws;
    u16*    W1p   = (u16*)ws;                      // 196608 B
    u16*    W2p   = (u16*)(ws + 196608);           // 131072 B
    float4* pos4  = (float4*)(ws + 327680);        // 65536 B

    prep_kernel<<<80, 256, 0, stream>>>(W1, W2, W1p, W2p, pos, pos4);
    mega_kernel<<<NSKIP / 32, 1024, 0, stream>>>(x, x_skip, pos4, batch,
                                                 W1p, b1, W2p, b2,
                                                 pos_skip, batch_skip, out);
}